// Round 6
// baseline (512.493 us; speedup 1.0000x reference)
//
#include <hip/hip_runtime.h>

#define NN 50000
#define NPAD 50048   // rows padded to multiple of 64 for MFMA tiles
#define NE 800000
#define FIN 64
#define H 128
#define NG 16
#define POOL_BLOCKS 200
#define POOL_NODES 250
#define SCAN_BLOCKS 196  // ceil(NN/256)

// ranged fill: 8 dst ranges (XCD-local) x 32 edge chunks
#define FILL_RANGES 8
#define RANGE_SZ 6250        // NN / FILL_RANGES
#define FILL_CHUNKS 32
#define FILL_CHUNK 25000     // NE / FILL_CHUNKS

typedef __bf16 bf16x8 __attribute__((ext_vector_type(8)));
typedef float f32x4 __attribute__((ext_vector_type(4)));

// ---- helpers ----
__device__ inline unsigned short bf16r(float x) {
    unsigned int u = __float_as_uint(x);
    return (unsigned short)((u + 0x7fffu + ((u >> 16) & 1u)) >> 16);
}
__device__ inline unsigned int pack_bf16x2(float a, float b) {
    return (unsigned int)bf16r(a) | ((unsigned int)bf16r(b) << 16);
}
__device__ inline float bf_lo(unsigned int u) { return __uint_as_float(u << 16); }
__device__ inline float bf_hi(unsigned int u) { return __uint_as_float(u & 0xffff0000u); }

// ================= CSR build =================
__global__ __launch_bounds__(256) void hist_kernel(const int* __restrict__ dst,
                                                   int* __restrict__ cnt) {
    int e = blockIdx.x * 256 + threadIdx.x;
    if (e < NE) atomicAdd(&cnt[dst[e]], 1);
}

__global__ __launch_bounds__(256) void scanA_kernel(const int* __restrict__ cnt,
                                                    int* __restrict__ bsum) {
    __shared__ int red[4];
    int i = blockIdx.x * 256 + threadIdx.x;
    int v = (i < NN) ? cnt[i] : 0;
    for (int off = 32; off > 0; off >>= 1) v += __shfl_down(v, off);
    if ((threadIdx.x & 63) == 0) red[threadIdx.x >> 6] = v;
    __syncthreads();
    if (threadIdx.x == 0) bsum[blockIdx.x] = red[0] + red[1] + red[2] + red[3];
}

__global__ __launch_bounds__(256) void scanB_kernel(int* __restrict__ bsum) {
    __shared__ int s[256];
    int t = threadIdx.x;
    int v = (t < SCAN_BLOCKS) ? bsum[t] : 0;
    s[t] = v;
    __syncthreads();
    for (int off = 1; off < 256; off <<= 1) {
        int u = (t >= off) ? s[t - off] : 0;
        __syncthreads();
        s[t] += u;
        __syncthreads();
    }
    if (t < SCAN_BLOCKS) bsum[t] = s[t] - v;  // exclusive
}

__global__ __launch_bounds__(256) void scanC_kernel(const int* __restrict__ cnt,
                                                    const int* __restrict__ bsum,
                                                    int* __restrict__ rowptr,
                                                    int* __restrict__ cursor) {
    __shared__ int s[256];
    int t = threadIdx.x;
    int i = blockIdx.x * 256 + t;
    int v = (i < NN) ? cnt[i] : 0;
    s[t] = v;
    __syncthreads();
    for (int off = 1; off < 256; off <<= 1) {
        int u = (t >= off) ? s[t - off] : 0;
        __syncthreads();
        s[t] += u;
        __syncthreads();
    }
    if (i < NN) {
        int ex = bsum[blockIdx.x] + s[t] - v;
        rowptr[i] = ex;
        cursor[i] = ex;
    }
    if (i == NN - 1) rowptr[NN] = NE;
}

__global__ __launch_bounds__(256) void dinv_kernel(const int* __restrict__ cnt,
                                                   float* __restrict__ dinv) {
    int i = blockIdx.x * 256 + threadIdx.x;
    if (i < NN) dinv[i] = rsqrtf((float)cnt[i] + 1.0f);  // +1 self-loop
}

// ranged fill: block (range = blockIdx&7, chunk = blockIdx>>3). All csr writes
// for a dst range come from blocks on (heuristically) one XCD -> stores merge
// in that XCD's L2 instead of one 64B line-writeback per edge.
__global__ __launch_bounds__(256) void fill_kernel(const int* __restrict__ ei,
                                                   int* __restrict__ cursor,
                                                   int* __restrict__ csr) {
    const int range = blockIdx.x & (FILL_RANGES - 1);
    const int chunk = blockIdx.x >> 3;
    const int lo = range * RANGE_SZ;
    const int hi = lo + RANGE_SZ;  // last range covers through NN (RANGE_SZ*8 = NN)
    const int e0 = chunk * FILL_CHUNK;
    const int e1 = e0 + FILL_CHUNK;
    for (int e = e0 + threadIdx.x; e < e1; e += 256) {
        int d = ei[NE + e];
        if (d >= lo && d < hi) {
            int s = ei[e];
            int pos = atomicAdd(&cursor[d], 1);
            csr[pos] = s;
        }
    }
}

// ================= converts =================
__global__ __launch_bounds__(256) void cvt_x_kernel(const float* __restrict__ x,
                                                    unsigned short* __restrict__ xb) {
    int e = blockIdx.x * 256 + threadIdx.x;  // NPAD*64
    if (e >= NPAD * FIN) return;
    xb[e] = (e < NN * FIN) ? bf16r(x[e]) : (unsigned short)0;
}

// Wt[n*K+k] = bf16(W[k*H + n])  (transpose + convert; weights are tiny)
template <int K>
__global__ __launch_bounds__(256) void cvt_w_kernel(const float* __restrict__ W,
                                                    unsigned short* __restrict__ Wt) {
    int t = blockIdx.x * 256 + threadIdx.x;  // H*K
    if (t >= H * K) return;
    int n = t / K, k = t % K;
    Wt[t] = bf16r(W[k * H + n]);
}

// ===== MFMA GEMM: out_bf16[NPAD,H] = (h_bf16[NPAD,K] @ W[K,H]) * dinv[row] =====
template <int K>
__global__ __launch_bounds__(256) void gemm_mfma_kernel(const unsigned short* __restrict__ hb,
                                                        const unsigned short* __restrict__ Wt,
                                                        const float* __restrict__ dinv,
                                                        unsigned short* __restrict__ out) {
    const int wave = threadIdx.x >> 6, lane = threadIdx.x & 63;
    const int m15 = lane & 15, quad = lane >> 4;
    const int arow = blockIdx.x * 64 + wave * 16 + m15;

    bf16x8 a[K / 32];
#pragma unroll
    for (int ks = 0; ks < K / 32; ks++)
        a[ks] = *(const bf16x8*)&hb[(size_t)arow * K + ks * 32 + quad * 8];

    const int rbase = blockIdx.x * 64 + wave * 16 + quad * 4;
    float dv[4];
#pragma unroll
    for (int r = 0; r < 4; r++) dv[r] = dinv[rbase + r];

#pragma unroll
    for (int ct = 0; ct < 8; ct++) {
        f32x4 acc = {0.f, 0.f, 0.f, 0.f};
#pragma unroll
        for (int ks = 0; ks < K / 32; ks++) {
            bf16x8 b = *(const bf16x8*)&Wt[(ct * 16 + m15) * K + ks * 32 + quad * 8];
            acc = __builtin_amdgcn_mfma_f32_16x16x32_bf16(a[ks], b, acc, 0, 0, 0);
        }
#pragma unroll
        for (int r = 0; r < 4; r++)
            out[(size_t)(rbase + r) * H + ct * 16 + m15] = bf16r(acc[r] * dv[r]);
    }
}

// ============ gather-side aggregation (pure sum; norms prescaled) ============
template <bool RELU_BIAS>
__global__ __launch_bounds__(256) void agg_kernel(const unsigned int* __restrict__ hwb,
                                                  const int* __restrict__ rowptr,
                                                  const int* __restrict__ csr,
                                                  const float* __restrict__ dinv,
                                                  const float* __restrict__ bias,
                                                  unsigned int* __restrict__ outb) {
    const int lane = threadIdx.x & 63;
    const int n = blockIdx.x * 4 + (threadIdx.x >> 6);

    unsigned int u = hwb[n * 64 + lane];
    float ax = bf_lo(u), ay = bf_hi(u);

    int beg = rowptr[n], end = rowptr[n + 1];
    int i = beg;
    // head: align csr index to 4
    for (; i < end && (i & 3); i++) {
        unsigned int ue = hwb[csr[i] * 64 + lane];
        ax += bf_lo(ue);
        ay += bf_hi(ue);
    }
    for (; i + 8 <= end; i += 8) {
        int4 ca = *(const int4*)&csr[i];
        int4 cb = *(const int4*)&csr[i + 4];
        unsigned int u0 = hwb[ca.x * 64 + lane], u1 = hwb[ca.y * 64 + lane];
        unsigned int u2 = hwb[ca.z * 64 + lane], u3 = hwb[ca.w * 64 + lane];
        unsigned int u4 = hwb[cb.x * 64 + lane], u5 = hwb[cb.y * 64 + lane];
        unsigned int u6 = hwb[cb.z * 64 + lane], u7 = hwb[cb.w * 64 + lane];
        ax += bf_lo(u0) + bf_lo(u1) + bf_lo(u2) + bf_lo(u3) +
              bf_lo(u4) + bf_lo(u5) + bf_lo(u6) + bf_lo(u7);
        ay += bf_hi(u0) + bf_hi(u1) + bf_hi(u2) + bf_hi(u3) +
              bf_hi(u4) + bf_hi(u5) + bf_hi(u6) + bf_hi(u7);
    }
    for (; i < end; i++) {
        unsigned int ue = hwb[csr[i] * 64 + lane];
        ax += bf_lo(ue);
        ay += bf_hi(ue);
    }
    float d = dinv[n];
    ax *= d;
    ay *= d;
    if (RELU_BIAS) {
        float2 bv = ((const float2*)bias)[lane];
        ax = fmaxf(ax + bv.x, 0.f);
        ay = fmaxf(ay + bv.y, 0.f);
    }
    outb[n * 64 + lane] = pack_bf16x2(ax, ay);
}

// ======== pooling: block-local segment reduction (batch sorted), bf16 in ========
__global__ __launch_bounds__(256) void pool_kernel(const unsigned int* __restrict__ hbu,
                                                   const float* __restrict__ b4,
                                                   const int* __restrict__ batch,
                                                   float* __restrict__ pooled,
                                                   float* __restrict__ cnt) {
    __shared__ int bs[POOL_NODES];
    const int tid = threadIdx.x;
    const int n0 = blockIdx.x * POOL_NODES;
    for (int i = tid; i < POOL_NODES; i += 256) bs[i] = batch[n0 + i];
    __syncthreads();
    const int c2 = tid & 63;
    const int rsub = tid >> 6;  // 0..3
    float2 bb = ((const float2*)b4)[c2];
    float2 acc = {0.f, 0.f};
    float cacc = 0.f;
    int curg = bs[rsub];
    for (int r = rsub; r < POOL_NODES; r += 4) {
        int g = bs[r];
        if (g != curg) {
            atomicAdd(&pooled[curg * H + c2 * 2], acc.x);
            atomicAdd(&pooled[curg * H + c2 * 2 + 1], acc.y);
            if (c2 == 0) atomicAdd(&cnt[curg], cacc);
            acc.x = acc.y = 0.f;
            cacc = 0.f;
            curg = g;
        }
        unsigned int v = hbu[(size_t)(n0 + r) * 64 + c2];
        acc.x += bf_lo(v) + bb.x;
        acc.y += bf_hi(v) + bb.y;
        cacc += 1.f;
    }
    atomicAdd(&pooled[curg * H + c2 * 2], acc.x);
    atomicAdd(&pooled[curg * H + c2 * 2 + 1], acc.y);
    if (c2 == 0) atomicAdd(&cnt[curg], cacc);
}

// ================= final MLP (single block) =================
__global__ __launch_bounds__(1024) void mlp_kernel(const float* __restrict__ pooled,
                                                   const float* __restrict__ cnt,
                                                   const float* __restrict__ lw1,
                                                   const float* __restrict__ lb1,
                                                   const float* __restrict__ lw2,
                                                   const float* __restrict__ lb2,
                                                   float* __restrict__ out) {
    __shared__ float mean_s[NG * H];
    __shared__ float hid_s[NG * 64];
    int tid = threadIdx.x;
    for (int i = tid; i < NG * H; i += 1024) {
        int g = i >> 7;
        mean_s[i] = pooled[i] / fmaxf(cnt[g], 1.0f);
    }
    __syncthreads();
    {
        int g = tid >> 6, j = tid & 63;
        float acc = lb1[j];
        for (int f = 0; f < H; f++) acc += mean_s[g * H + f] * lw1[f * 64 + j];
        hid_s[g * 64 + j] = fmaxf(acc, 0.f);
    }
    __syncthreads();
    if (tid < 32) {
        int g = tid >> 1, c = tid & 1;
        float acc = lb2[c];
        for (int j = 0; j < 64; j++) acc += hid_s[g * 64 + j] * lw2[j * 2 + c];
        out[g * 2 + c] = acc;
    }
}

extern "C" void kernel_launch(void* const* d_in, const int* in_sizes, int n_in,
                              void* d_out, int out_size, void* d_ws, size_t ws_size,
                              hipStream_t stream) {
    const float* x = (const float*)d_in[0];
    const int* ei = (const int*)d_in[1];
    const int* batch = (const int*)d_in[2];
    const float* W1 = (const float*)d_in[3];
    const float* b1 = (const float*)d_in[4];
    const float* W2 = (const float*)d_in[5];
    const float* b2 = (const float*)d_in[6];
    const float* W3 = (const float*)d_in[7];
    const float* b3 = (const float*)d_in[8];
    const float* W4 = (const float*)d_in[9];
    const float* b4 = (const float*)d_in[10];
    const float* lw1 = (const float*)d_in[11];
    const float* lb1 = (const float*)d_in[12];
    const float* lw2 = (const float*)d_in[13];
    const float* lb2 = (const float*)d_in[14];
    float* out = (float*)d_out;

    // workspace layout (4-byte units); total ~36.2 MB
    int* wsi = (int*)d_ws;
    int* cnt = wsi;                                        // 50048
    int* bsum = wsi + 50048;                               // 256
    int* rowptr = wsi + 50304;                             // 50016
    int* cursor = wsi + 100320;                            // 50048
    int* csr = wsi + 150368;                               // NE
    float* dinv = (float*)(wsi + 950368);                  // 50048
    unsigned short* Wt1 = (unsigned short*)(wsi + 1000416);  // 128*64
    unsigned short* Wt2 = (unsigned short*)(wsi + 1004512);  // 128*128
    unsigned short* Wt3 = (unsigned short*)(wsi + 1012704);
    unsigned short* Wt4 = (unsigned short*)(wsi + 1020896);
    unsigned short* xb = (unsigned short*)(wsi + 1029088);   // NPAD*64
    unsigned int* hb = (unsigned int*)(wsi + 2630624);       // NPAD*64 (bf16x2)
    unsigned int* hwb = (unsigned int*)(wsi + 5833696);      // NPAD*64
    float* pooled = (float*)(wsi + 9036768);                 // NG*H
    float* pcnt = pooled + NG * H;                           // NG

    const int nodeBlocks = (NN + 255) / 256;   // 196
    const int edgeBlocks = (NE + 255) / 256;   // 3125
    const int gemmBlocks = NPAD / 64;          // 782
    const int aggBlocks = NN / 4;              // 12500

    // ---- CSR build (once; reused by all 4 layers) ----
    hipMemsetAsync(cnt, 0, NN * sizeof(int), stream);
    hist_kernel<<<edgeBlocks, 256, 0, stream>>>(ei + NE, cnt);
    scanA_kernel<<<SCAN_BLOCKS, 256, 0, stream>>>(cnt, bsum);
    scanB_kernel<<<1, 256, 0, stream>>>(bsum);
    scanC_kernel<<<SCAN_BLOCKS, 256, 0, stream>>>(cnt, bsum, rowptr, cursor);
    dinv_kernel<<<nodeBlocks, 256, 0, stream>>>(cnt, dinv);
    fill_kernel<<<FILL_RANGES * FILL_CHUNKS, 256, 0, stream>>>(ei, cursor, csr);

    // ---- converts ----
    cvt_x_kernel<<<(NPAD * FIN) / 256, 256, 0, stream>>>(x, xb);
    cvt_w_kernel<FIN><<<(H * FIN) / 256, 256, 0, stream>>>(W1, Wt1);
    cvt_w_kernel<H><<<(H * H) / 256, 256, 0, stream>>>(W2, Wt2);
    cvt_w_kernel<H><<<(H * H) / 256, 256, 0, stream>>>(W3, Wt3);
    cvt_w_kernel<H><<<(H * H) / 256, 256, 0, stream>>>(W4, Wt4);

    // ---- layer 1 ----
    gemm_mfma_kernel<FIN><<<gemmBlocks, 256, 0, stream>>>(xb, Wt1, dinv, (unsigned short*)hwb);
    agg_kernel<true><<<aggBlocks, 256, 0, stream>>>(hwb, rowptr, csr, dinv, b1, hb);
    // ---- layer 2 ----
    gemm_mfma_kernel<H><<<gemmBlocks, 256, 0, stream>>>((unsigned short*)hb, Wt2, dinv, (unsigned short*)hwb);
    agg_kernel<true><<<aggBlocks, 256, 0, stream>>>(hwb, rowptr, csr, dinv, b2, hb);
    // ---- layer 3 ----
    gemm_mfma_kernel<H><<<gemmBlocks, 256, 0, stream>>>((unsigned short*)hb, Wt3, dinv, (unsigned short*)hwb);
    agg_kernel<true><<<aggBlocks, 256, 0, stream>>>(hwb, rowptr, csr, dinv, b3, hb);
    // ---- layer 4 (no relu/bias; b4 fused in pool) ----
    gemm_mfma_kernel<H><<<gemmBlocks, 256, 0, stream>>>((unsigned short*)hb, Wt4, dinv, (unsigned short*)hwb);
    agg_kernel<false><<<aggBlocks, 256, 0, stream>>>(hwb, rowptr, csr, dinv, nullptr, hb);

    // ---- pooling (fused +b4) + MLP ----
    hipMemsetAsync(pooled, 0, (NG * H + NG) * sizeof(float), stream);
    pool_kernel<<<POOL_BLOCKS, 256, 0, stream>>>(hb, b4, batch, pooled, pcnt);
    mlp_kernel<<<1, 1024, 0, stream>>>(pooled, pcnt, lw1, lb1, lw2, lb2, out);
}

// Round 7
// 484.273 us; speedup vs baseline: 1.0583x; 1.0583x over previous
//
#include <hip/hip_runtime.h>

#define NN 50000
#define NPAD 50048   // rows padded to multiple of 64 for MFMA tiles
#define NE 800000
#define FIN 64
#define H 128
#define NG 16
#define POOL_BLOCKS 200
#define POOL_NODES 250
#define SCAN_BLOCKS 196  // ceil(NN/256)
#define NBUCK 98         // buckets of 512 dst nodes
#define FILLA_BLOCKS 64
#define FILLA_CHUNK (NE / FILLA_BLOCKS)  // 12500

typedef __bf16 bf16x8 __attribute__((ext_vector_type(8)));
typedef float f32x4 __attribute__((ext_vector_type(4)));

// ---- helpers ----
__device__ inline unsigned short bf16r(float x) {
    unsigned int u = __float_as_uint(x);
    return (unsigned short)((u + 0x7fffu + ((u >> 16) & 1u)) >> 16);
}
__device__ inline unsigned int pack_bf16x2(float a, float b) {
    return (unsigned int)bf16r(a) | ((unsigned int)bf16r(b) << 16);
}
__device__ inline float bf_lo(unsigned int u) { return __uint_as_float(u << 16); }
__device__ inline float bf_hi(unsigned int u) { return __uint_as_float(u & 0xffff0000u); }

// ================= CSR build =================
__global__ __launch_bounds__(256) void hist_kernel(const int* __restrict__ dst,
                                                   int* __restrict__ cnt) {
    int e = blockIdx.x * 256 + threadIdx.x;
    if (e < NE) atomicAdd(&cnt[dst[e]], 1);
}

__global__ __launch_bounds__(256) void scanA_kernel(const int* __restrict__ cnt,
                                                    int* __restrict__ bsum) {
    __shared__ int red[4];
    int i = blockIdx.x * 256 + threadIdx.x;
    int v = (i < NN) ? cnt[i] : 0;
    for (int off = 32; off > 0; off >>= 1) v += __shfl_down(v, off);
    if ((threadIdx.x & 63) == 0) red[threadIdx.x >> 6] = v;
    __syncthreads();
    if (threadIdx.x == 0) bsum[blockIdx.x] = red[0] + red[1] + red[2] + red[3];
}

__global__ __launch_bounds__(256) void scanB_kernel(int* __restrict__ bsum) {
    __shared__ int s[256];
    int t = threadIdx.x;
    int v = (t < SCAN_BLOCKS) ? bsum[t] : 0;
    s[t] = v;
    __syncthreads();
    for (int off = 1; off < 256; off <<= 1) {
        int u = (t >= off) ? s[t - off] : 0;
        __syncthreads();
        s[t] += u;
        __syncthreads();
    }
    if (t < SCAN_BLOCKS) bsum[t] = s[t] - v;  // exclusive
}

// scanC: rowptr/cursor + dinv + bucket bases (gbase[b] = rowptr[b*512])
__global__ __launch_bounds__(256) void scanC_kernel(const int* __restrict__ cnt,
                                                    const int* __restrict__ bsum,
                                                    int* __restrict__ rowptr,
                                                    int* __restrict__ cursor,
                                                    float* __restrict__ dinv,
                                                    int* __restrict__ gbase) {
    __shared__ int s[256];
    int t = threadIdx.x;
    int i = blockIdx.x * 256 + t;
    int v = (i < NN) ? cnt[i] : 0;
    s[t] = v;
    __syncthreads();
    for (int off = 1; off < 256; off <<= 1) {
        int u = (t >= off) ? s[t - off] : 0;
        __syncthreads();
        s[t] += u;
        __syncthreads();
    }
    if (i < NN) {
        int ex = bsum[blockIdx.x] + s[t] - v;
        rowptr[i] = ex;
        cursor[i] = ex;
        dinv[i] = rsqrtf((float)v + 1.0f);  // +1 self-loop
        if ((i & 511) == 0) gbase[i >> 9] = ex;
    }
    if (i == NN - 1) rowptr[NN] = NE;
}

// fillA: bucket edges by dst>>9. LDS hist -> one global reserve per
// (block,bucket) -> append packed (dst<<16)|src. Appends are contiguous runs
// per bucket, so stores merge (no per-store line churn).
__global__ __launch_bounds__(256) void fillA_kernel(const int* __restrict__ ei,
                                                    int* __restrict__ gbase,
                                                    unsigned int* __restrict__ ebuf) {
    __shared__ int hist[128];
    __shared__ int base[128];
    const int t = threadIdx.x;
    if (t < 128) hist[t] = 0;
    __syncthreads();
    const int e0 = blockIdx.x * FILLA_CHUNK;
    for (int e = e0 + t; e < e0 + FILLA_CHUNK; e += 256)
        atomicAdd(&hist[ei[NE + e] >> 9], 1);
    __syncthreads();
    if (t < 128) {
        int h = (t < NBUCK) ? hist[t] : 0;
        base[t] = h ? atomicAdd(&gbase[t], h) : 0;
    }
    __syncthreads();
    for (int e = e0 + t; e < e0 + FILLA_CHUNK; e += 256) {
        int d = ei[NE + e];
        int s = ei[e];
        int pos = atomicAdd(&base[d >> 9], 1);
        ebuf[pos] = (unsigned int)s | ((unsigned int)d << 16);
    }
}

// fillB: one block per bucket; scatter within the bucket's csr window
// (~32 KB, single-block-local -> L2-resident, merged writeback).
__global__ __launch_bounds__(256) void fillB_kernel(const unsigned int* __restrict__ ebuf,
                                                    const int* __restrict__ rowptr,
                                                    int* __restrict__ cursor,
                                                    int* __restrict__ csr) {
    const int b = blockIdx.x;
    const int lo = rowptr[b * 512];
    const int nhi = min((b + 1) * 512, NN);
    const int hi = rowptr[nhi];
    for (int i = lo + threadIdx.x; i < hi; i += 256) {
        unsigned int p = ebuf[i];
        int s = (int)(p & 0xFFFFu);
        int d = (int)(p >> 16);
        int pos = atomicAdd(&cursor[d], 1);
        csr[pos] = s;
    }
}

// ================= converts =================
__global__ __launch_bounds__(256) void cvt_x_kernel(const float* __restrict__ x,
                                                    unsigned short* __restrict__ xb) {
    int e = blockIdx.x * 256 + threadIdx.x;  // NPAD*64
    if (e >= NPAD * FIN) return;
    xb[e] = (e < NN * FIN) ? bf16r(x[e]) : (unsigned short)0;
}

// all four weight transposes in one launch. Wt[n*K+k] = bf16(W[k*H+n])
__global__ __launch_bounds__(256) void cvt_w_all_kernel(const float* __restrict__ W1,
                                                        const float* __restrict__ W2,
                                                        const float* __restrict__ W3,
                                                        const float* __restrict__ W4,
                                                        unsigned short* __restrict__ Wt1,
                                                        unsigned short* __restrict__ Wt2,
                                                        unsigned short* __restrict__ Wt3,
                                                        unsigned short* __restrict__ Wt4) {
    int t = blockIdx.x * 256 + threadIdx.x;
    if (t < H * FIN) {
        int n = t / FIN, k = t % FIN;
        Wt1[t] = bf16r(W1[k * H + n]);
        return;
    }
    int u = t - H * FIN;
    const float* W = W2;
    unsigned short* Wt = Wt2;
    if (u >= 2 * H * H) { W = W4; Wt = Wt4; u -= 2 * H * H; }
    else if (u >= H * H) { W = W3; Wt = Wt3; u -= H * H; }
    if (u < H * H) {
        int n = u / H, k = u % H;
        Wt[u] = bf16r(W[k * H + n]);
    }
}

// ===== MFMA GEMM: out_bf16[NPAD,H] = (h_bf16[NPAD,K] @ W[K,H]) * dinv[row] =====
template <int K>
__global__ __launch_bounds__(256) void gemm_mfma_kernel(const unsigned short* __restrict__ hb,
                                                        const unsigned short* __restrict__ Wt,
                                                        const float* __restrict__ dinv,
                                                        unsigned short* __restrict__ out) {
    const int wave = threadIdx.x >> 6, lane = threadIdx.x & 63;
    const int m15 = lane & 15, quad = lane >> 4;
    const int arow = blockIdx.x * 64 + wave * 16 + m15;

    bf16x8 a[K / 32];
#pragma unroll
    for (int ks = 0; ks < K / 32; ks++)
        a[ks] = *(const bf16x8*)&hb[(size_t)arow * K + ks * 32 + quad * 8];

    const int rbase = blockIdx.x * 64 + wave * 16 + quad * 4;
    float dv[4];
#pragma unroll
    for (int r = 0; r < 4; r++) dv[r] = dinv[rbase + r];

#pragma unroll
    for (int ct = 0; ct < 8; ct++) {
        f32x4 acc = {0.f, 0.f, 0.f, 0.f};
#pragma unroll
        for (int ks = 0; ks < K / 32; ks++) {
            bf16x8 b = *(const bf16x8*)&Wt[(ct * 16 + m15) * K + ks * 32 + quad * 8];
            acc = __builtin_amdgcn_mfma_f32_16x16x32_bf16(a[ks], b, acc, 0, 0, 0);
        }
#pragma unroll
        for (int r = 0; r < 4; r++)
            out[(size_t)(rbase + r) * H + ct * 16 + m15] = bf16r(acc[r] * dv[r]);
    }
}

// ============ gather-side aggregation (pure sum; norms prescaled) ============
template <bool RELU_BIAS>
__global__ __launch_bounds__(256) void agg_kernel(const unsigned int* __restrict__ hwb,
                                                  const int* __restrict__ rowptr,
                                                  const int* __restrict__ csr,
                                                  const float* __restrict__ dinv,
                                                  const float* __restrict__ bias,
                                                  unsigned int* __restrict__ outb) {
    const int lane = threadIdx.x & 63;
    const int n = blockIdx.x * 4 + (threadIdx.x >> 6);

    unsigned int u = hwb[n * 64 + lane];
    float ax = bf_lo(u), ay = bf_hi(u);

    int beg = rowptr[n], end = rowptr[n + 1];
    int i = beg;
    for (; i < end && (i & 3); i++) {
        unsigned int ue = hwb[csr[i] * 64 + lane];
        ax += bf_lo(ue);
        ay += bf_hi(ue);
    }
    for (; i + 8 <= end; i += 8) {
        int4 ca = *(const int4*)&csr[i];
        int4 cb = *(const int4*)&csr[i + 4];
        unsigned int u0 = hwb[ca.x * 64 + lane], u1 = hwb[ca.y * 64 + lane];
        unsigned int u2 = hwb[ca.z * 64 + lane], u3 = hwb[ca.w * 64 + lane];
        unsigned int u4 = hwb[cb.x * 64 + lane], u5 = hwb[cb.y * 64 + lane];
        unsigned int u6 = hwb[cb.z * 64 + lane], u7 = hwb[cb.w * 64 + lane];
        ax += bf_lo(u0) + bf_lo(u1) + bf_lo(u2) + bf_lo(u3) +
              bf_lo(u4) + bf_lo(u5) + bf_lo(u6) + bf_lo(u7);
        ay += bf_hi(u0) + bf_hi(u1) + bf_hi(u2) + bf_hi(u3) +
              bf_hi(u4) + bf_hi(u5) + bf_hi(u6) + bf_hi(u7);
    }
    for (; i < end; i++) {
        unsigned int ue = hwb[csr[i] * 64 + lane];
        ax += bf_lo(ue);
        ay += bf_hi(ue);
    }
    float d = dinv[n];
    ax *= d;
    ay *= d;
    if (RELU_BIAS) {
        float2 bv = ((const float2*)bias)[lane];
        ax = fmaxf(ax + bv.x, 0.f);
        ay = fmaxf(ay + bv.y, 0.f);
    }
    outb[n * 64 + lane] = pack_bf16x2(ax, ay);
}

// ======== pooling: block-local segment reduction (batch sorted), bf16 in ========
__global__ __launch_bounds__(256) void pool_kernel(const unsigned int* __restrict__ hbu,
                                                   const float* __restrict__ b4,
                                                   const int* __restrict__ batch,
                                                   float* __restrict__ pooled,
                                                   float* __restrict__ cnt) {
    __shared__ int bs[POOL_NODES];
    const int tid = threadIdx.x;
    const int n0 = blockIdx.x * POOL_NODES;
    for (int i = tid; i < POOL_NODES; i += 256) bs[i] = batch[n0 + i];
    __syncthreads();
    const int c2 = tid & 63;
    const int rsub = tid >> 6;  // 0..3
    float2 bb = ((const float2*)b4)[c2];
    float2 acc = {0.f, 0.f};
    float cacc = 0.f;
    int curg = bs[rsub];
    for (int r = rsub; r < POOL_NODES; r += 4) {
        int g = bs[r];
        if (g != curg) {
            atomicAdd(&pooled[curg * H + c2 * 2], acc.x);
            atomicAdd(&pooled[curg * H + c2 * 2 + 1], acc.y);
            if (c2 == 0) atomicAdd(&cnt[curg], cacc);
            acc.x = acc.y = 0.f;
            cacc = 0.f;
            curg = g;
        }
        unsigned int v = hbu[(size_t)(n0 + r) * 64 + c2];
        acc.x += bf_lo(v) + bb.x;
        acc.y += bf_hi(v) + bb.y;
        cacc += 1.f;
    }
    atomicAdd(&pooled[curg * H + c2 * 2], acc.x);
    atomicAdd(&pooled[curg * H + c2 * 2 + 1], acc.y);
    if (c2 == 0) atomicAdd(&cnt[curg], cacc);
}

// ================= final MLP (single block) =================
__global__ __launch_bounds__(1024) void mlp_kernel(const float* __restrict__ pooled,
                                                   const float* __restrict__ cnt,
                                                   const float* __restrict__ lw1,
                                                   const float* __restrict__ lb1,
                                                   const float* __restrict__ lw2,
                                                   const float* __restrict__ lb2,
                                                   float* __restrict__ out) {
    __shared__ float mean_s[NG * H];
    __shared__ float hid_s[NG * 64];
    int tid = threadIdx.x;
    for (int i = tid; i < NG * H; i += 1024) {
        int g = i >> 7;
        mean_s[i] = pooled[i] / fmaxf(cnt[g], 1.0f);
    }
    __syncthreads();
    {
        int g = tid >> 6, j = tid & 63;
        float acc = lb1[j];
        for (int f = 0; f < H; f++) acc += mean_s[g * H + f] * lw1[f * 64 + j];
        hid_s[g * 64 + j] = fmaxf(acc, 0.f);
    }
    __syncthreads();
    if (tid < 32) {
        int g = tid >> 1, c = tid & 1;
        float acc = lb2[c];
        for (int j = 0; j < 64; j++) acc += hid_s[g * 64 + j] * lw2[j * 2 + c];
        out[g * 2 + c] = acc;
    }
}

extern "C" void kernel_launch(void* const* d_in, const int* in_sizes, int n_in,
                              void* d_out, int out_size, void* d_ws, size_t ws_size,
                              hipStream_t stream) {
    const float* x = (const float*)d_in[0];
    const int* ei = (const int*)d_in[1];
    const int* batch = (const int*)d_in[2];
    const float* W1 = (const float*)d_in[3];
    const float* b1 = (const float*)d_in[4];
    const float* W2 = (const float*)d_in[5];
    const float* b2 = (const float*)d_in[6];
    const float* W3 = (const float*)d_in[7];
    const float* b3 = (const float*)d_in[8];
    const float* W4 = (const float*)d_in[9];
    const float* b4 = (const float*)d_in[10];
    const float* lw1 = (const float*)d_in[11];
    const float* lb1 = (const float*)d_in[12];
    const float* lw2 = (const float*)d_in[13];
    const float* lb2 = (const float*)d_in[14];
    float* out = (float*)d_out;

    // workspace layout (4-byte units); total ~40 MB
    int* wsi = (int*)d_ws;
    int* cnt = wsi;                                        // 50048
    int* bsum = wsi + 50048;                               // 256
    int* rowptr = wsi + 50304;                             // 50016
    int* cursor = wsi + 100320;                            // 50048
    int* csr = wsi + 150368;                               // NE
    float* dinv = (float*)(wsi + 950368);                  // 50048
    unsigned short* Wt1 = (unsigned short*)(wsi + 1000416);  // 128*64
    unsigned short* Wt2 = (unsigned short*)(wsi + 1004512);  // 128*128
    unsigned short* Wt3 = (unsigned short*)(wsi + 1012704);
    unsigned short* Wt4 = (unsigned short*)(wsi + 1020896);
    unsigned short* xb = (unsigned short*)(wsi + 1029088);   // NPAD*64
    unsigned int* hb = (unsigned int*)(wsi + 2630624);       // NPAD*64 (bf16x2)
    unsigned int* hwb = (unsigned int*)(wsi + 5833696);      // NPAD*64
    float* pooled = (float*)(wsi + 9036768);                 // NG*H
    float* pcnt = pooled + NG * H;                           // NG
    int* gbase = wsi + 9038928;                              // 128
    unsigned int* ebuf = (unsigned int*)(wsi + 9039056);     // NE

    const int edgeBlocks = (NE + 255) / 256;   // 3125
    const int gemmBlocks = NPAD / 64;          // 782
    const int aggBlocks = NN / 4;              // 12500

    // ---- CSR build (once; reused by all 4 layers) ----
    hipMemsetAsync(cnt, 0, NN * sizeof(int), stream);
    hist_kernel<<<edgeBlocks, 256, 0, stream>>>(ei + NE, cnt);
    scanA_kernel<<<SCAN_BLOCKS, 256, 0, stream>>>(cnt, bsum);
    scanB_kernel<<<1, 256, 0, stream>>>(bsum);
    scanC_kernel<<<SCAN_BLOCKS, 256, 0, stream>>>(cnt, bsum, rowptr, cursor, dinv, gbase);
    fillA_kernel<<<FILLA_BLOCKS, 256, 0, stream>>>(ei, gbase, ebuf);
    fillB_kernel<<<NBUCK, 256, 0, stream>>>(ebuf, rowptr, cursor, csr);

    // ---- converts ----
    cvt_x_kernel<<<(NPAD * FIN) / 256, 256, 0, stream>>>(x, xb);
    cvt_w_all_kernel<<<(H * FIN + 3 * H * H) / 256, 256, 0, stream>>>(
        W1, W2, W3, W4, Wt1, Wt2, Wt3, Wt4);

    // ---- layer 1 ----
    gemm_mfma_kernel<FIN><<<gemmBlocks, 256, 0, stream>>>(xb, Wt1, dinv, (unsigned short*)hwb);
    agg_kernel<true><<<aggBlocks, 256, 0, stream>>>(hwb, rowptr, csr, dinv, b1, hb);
    // ---- layer 2 ----
    gemm_mfma_kernel<H><<<gemmBlocks, 256, 0, stream>>>((unsigned short*)hb, Wt2, dinv, (unsigned short*)hwb);
    agg_kernel<true><<<aggBlocks, 256, 0, stream>>>(hwb, rowptr, csr, dinv, b2, hb);
    // ---- layer 3 ----
    gemm_mfma_kernel<H><<<gemmBlocks, 256, 0, stream>>>((unsigned short*)hb, Wt3, dinv, (unsigned short*)hwb);
    agg_kernel<true><<<aggBlocks, 256, 0, stream>>>(hwb, rowptr, csr, dinv, b3, hb);
    // ---- layer 4 (no relu/bias; b4 fused in pool) ----
    gemm_mfma_kernel<H><<<gemmBlocks, 256, 0, stream>>>((unsigned short*)hb, Wt4, dinv, (unsigned short*)hwb);
    agg_kernel<false><<<aggBlocks, 256, 0, stream>>>(hwb, rowptr, csr, dinv, nullptr, hb);

    // ---- pooling (fused +b4) + MLP ----
    hipMemsetAsync(pooled, 0, (NG * H + NG) * sizeof(float), stream);
    pool_kernel<<<POOL_BLOCKS, 256, 0, stream>>>(hb, b4, batch, pooled, pcnt);
    mlp_kernel<<<1, 1024, 0, stream>>>(pooled, pcnt, lw1, lb1, lw2, lb2, out);
}